// Round 15
// baseline (173.023 us; speedup 1.0000x reference)
//
#include <hip/hip_runtime.h>
#include <hip/hip_bf16.h>
#include <math.h>

#define LQN 1024
#define LKN 1024
#define NB 16
#define DM 160
#define NHEADS 8
#define HDIM 20

typedef __attribute__((ext_vector_type(8))) short bf16x8;
typedef __attribute__((ext_vector_type(4))) float f32x4;

__device__ __forceinline__ float bf2f(unsigned short h) {
  union { unsigned int u; float f; } c; c.u = ((unsigned int)h) << 16; return c.f;
}
__device__ __forceinline__ unsigned short f2bf(float f) {
  union { float f; unsigned int u; } c; c.f = f;
  unsigned int lsb = (c.u >> 16) & 1u;
  unsigned int r = c.u + 0x7fffu + lsb;
  return (unsigned short)(r >> 16);
}
__device__ __forceinline__ unsigned int cvtpk(float a, float b) {
  unsigned int r;
  asm("v_cvt_pk_bf16_f32 %0, %1, %2" : "=v"(r) : "v"(a), "v"(b));
  return r;
}
__device__ __forceinline__ float ex2(float x) { return __builtin_amdgcn_exp2f(x); }

struct CvtArgs {
  const float* src[8];
  int cum[9];
};

// ---- fused init + dual input LayerNorm ----
__global__ void init_kernel(uint4* __restrict__ zbase, int nz,
                            uint4* __restrict__ vbase, int nv,
                            const float* __restrict__ b0,
                            const float* __restrict__ b1,
                            const float* __restrict__ b2,
                            float* __restrict__ bcat,
                            CvtArgs a, unsigned short* __restrict__ wdst,
                            const float* __restrict__ x1,
                            const float* __restrict__ g1,
                            const float* __restrict__ bb1,
                            unsigned short* __restrict__ y1,
                            const float* __restrict__ x2,
                            const float* __restrict__ g2,
                            const float* __restrict__ bb2,
                            unsigned short* __restrict__ y2, int rowsPer) {
  int i = blockIdx.x * 256 + threadIdx.x;
  if (i < nz) zbase[i] = make_uint4(0, 0, 0, 0);
  if (i < nv) {
    unsigned int v = ((i & 31) == 20) ? 0x3F803F80u : 0u;
    vbase[i] = make_uint4(v, v, v, v);
  }
  if (i < 480) bcat[i] = (i < 160) ? b0[i] : (i < 320 ? b1[i - 160] : b2[i - 320]);
  if (i < 409600) {
    int s = 0;
#pragma unroll
    for (int t = 0; t < 7; ++t) s += (i >= a.cum[t + 1]) ? 1 : 0;
    wdst[i] = f2bf(a.src[s][i - a.cum[s]]);
  }
  int row = blockIdx.x * 4 + (threadIdx.x >> 6);
  int lane = threadIdx.x & 63;
  const float* x; const float* g; const float* b; unsigned short* y;
  if (row < rowsPer) {
    x = x1 + (size_t)row * DM; g = g1; b = bb1; y = y1 + (size_t)row * DM;
  } else {
    int r2 = row - rowsPer;
    x = x2 + (size_t)r2 * DM; g = g2; b = bb2; y = y2 + (size_t)r2 * DM;
  }
  float a0 = x[lane];
  float a1 = x[lane + 64];
  float a2 = (lane < 32) ? x[lane + 128] : 0.0f;
  float s = a0 + a1 + a2;
#pragma unroll
  for (int m = 1; m < 64; m <<= 1) s += __shfl_xor(s, m);
  float mean = s * (1.0f / DM);
  float d0 = a0 - mean, d1 = a1 - mean, d2 = a2 - mean;
  float vs = d0 * d0 + d1 * d1 + ((lane < 32) ? d2 * d2 : 0.0f);
#pragma unroll
  for (int m = 1; m < 64; m <<= 1) vs += __shfl_xor(vs, m);
  float rstd = rsqrtf(vs * (1.0f / DM) + 1e-5f);
  y[lane]      = f2bf(d0 * rstd * g[lane]      + b[lane]);
  y[lane + 64] = f2bf(d1 * rstd * g[lane + 64] + b[lane + 64]);
  if (lane < 32)
    y[lane + 128] = f2bf(d2 * rstd * g[lane + 128] + b[lane + 128]);
}

// ============ LDS-W GEMM: 64 rows x NCOL*16 cols per block, K=160 ============
template <int EPI, int NCOL>
__global__ __launch_bounds__(256, 2)
void gemm160_kernel(const unsigned short* __restrict__ Aq,
                    const unsigned short* __restrict__ Akv,
                    const unsigned short* __restrict__ W,
                    const float* __restrict__ bias,
                    const float* __restrict__ res,
                    void* __restrict__ outp,
                    unsigned short* __restrict__ Kc,
                    unsigned short* __restrict__ Vc,
                    const float* __restrict__ lng,
                    const float* __restrict__ lnb) {
  __shared__ unsigned short wl[NCOL * 16 * 168];
  int tid = threadIdx.x;
  int lane = tid & 63;
  int w = tid >> 6;
  int y = blockIdx.y;
  const unsigned short* Wb = W + y * (NCOL * 2560);
  for (int idx = tid * 8; idx < NCOL * 2560; idx += 2048) {
    int col = idx / 160, k = idx % 160;
    *(uint4*)(wl + col * 168 + k) = *(const uint4*)(Wb + idx);
  }
  __syncthreads();
  int lr = lane & 15;
  int g = lane >> 4;
  int R0 = blockIdx.x * 64;
  int rbase = R0 + w * 16;
  const unsigned short* A = (EPI == 0 && y > 0) ? Akv : Aq;
  const unsigned short* Ap = A + (size_t)(rbase + lr) * 160 + g * 8;
  const unsigned short* wp = wl + lr * 168 + g * 8;
  f32x4 acc[NCOL];
#pragma unroll
  for (int c = 0; c < NCOL; ++c) acc[c] = (f32x4){0, 0, 0, 0};
#pragma unroll
  for (int k0 = 0; k0 < 160; k0 += 32) {
    bf16x8 a = *(const bf16x8*)(Ap + k0);
#pragma unroll
    for (int c = 0; c < NCOL; ++c) {
      bf16x8 bfr = *(const bf16x8*)(wp + c * 16 * 168 + k0);
      acc[c] = __builtin_amdgcn_mfma_f32_16x16x32_bf16(a, bfr, acc[c], 0, 0, 0);
    }
  }
  if (EPI == 0) {
    if (y == 0) {
      unsigned short* Qp = (unsigned short*)outp;
#pragma unroll
      for (int c = 0; c < NCOL; ++c) {
        int col = c * 16 + lr;
        int h = col / 20, d = col % 20;
        float bc = bias[col];
#pragma unroll
        for (int r = 0; r < 4; ++r) {
          int row = rbase + g * 4 + r;
          Qp[(size_t)row * 256 + h * 32 + d] = f2bf(acc[c][r] + bc);
        }
      }
    } else if (y == 1) {
      int b = R0 >> 10;
#pragma unroll
      for (int c = 0; c < NCOL; ++c) {
        int col = c * 16 + lr;
        int h = col / 20, d = col % 20;
        float bc = bias[160 + col];
        size_t base = ((((size_t)(b * 8 + h)) * 4 + (d >> 3)) * 1024) * 8 + (d & 7);
#pragma unroll
        for (int r = 0; r < 4; ++r) {
          int tok = (rbase + g * 4 + r) & 1023;
          Kc[base + (size_t)tok * 8] = f2bf(acc[c][r] + bc);
        }
      }
    } else {
      int b = R0 >> 10;
      int base64 = R0 & 1023;
      int slotbase = base64 + g * 8 + (w & 1) * 4 + (w >> 1) * 32;
#pragma unroll
      for (int c = 0; c < NCOL; ++c) {
        int col = c * 16 + lr;
        int h = col / 20, d = col % 20;
        float bc = bias[320 + col];
        size_t vb = ((size_t)(b * 8 + h) * 128) * 256 + (size_t)d * 8;
#pragma unroll
        for (int r = 0; r < 4; ++r) {
          int S = slotbase + r;
          Vc[vb + (size_t)(S >> 3) * 256 + (S & 7)] = f2bf(acc[c][r] + bc);
        }
      }
    }
  } else if (EPI == 2) {
    unsigned short* out = (unsigned short*)outp;
#pragma unroll
    for (int c = 0; c < NCOL; ++c) {
      int colg = y * NCOL * 16 + c * 16 + lr;
      float bc = bias[colg];
#pragma unroll
      for (int r = 0; r < 4; ++r) {
        int row = rbase + g * 4 + r;
        float v = acc[c][r] + bc;
        v = 0.5f * v * (1.0f + erff(v * 0.70710678118654752f));
        out[(size_t)row * 640 + colg] = f2bf(v);
      }
    }
  } else {
    float* out = (float*)outp;
#pragma unroll
    for (int c = 0; c < NCOL; ++c) {
      int col = c * 16 + lr;
      float bc = bias[col];
#pragma unroll
      for (int r = 0; r < 4; ++r) {
        int row = rbase + g * 4 + r;
        float v = acc[c][r] + bc + res[(size_t)row * 160 + col];
        acc[c][r] = v;
        out[(size_t)row * 160 + col] = v;
      }
    }
#pragma unroll
    for (int r = 0; r < 4; ++r) {
      float s = 0.0f, sq = 0.0f;
#pragma unroll
      for (int c = 0; c < NCOL; ++c) { s += acc[c][r]; sq += acc[c][r] * acc[c][r]; }
#pragma unroll
      for (int m = 1; m < 16; m <<= 1) { s += __shfl_xor(s, m); sq += __shfl_xor(sq, m); }
      float mean = s * (1.0f / DM);
      float var = sq * (1.0f / DM) - mean * mean;
      float rstd = rsqrtf(var + 1e-5f);
      int row = rbase + g * 4 + r;
#pragma unroll
      for (int c = 0; c < NCOL; ++c) {
        int col = c * 16 + lr;
        Kc[(size_t)row * 160 + col] =
            f2bf((acc[c][r] - mean) * rstd * lng[col] + lnb[col]);
      }
    }
  }
}

// ---------------- old-style GEMM for w2 (K=640) ----------------
template <int K>
__global__ __launch_bounds__(256, 4)
void gemm_kernel(const unsigned short* __restrict__ A,
                 const unsigned short* __restrict__ W,
                 const float* __restrict__ bias,
                 const float* __restrict__ res,
                 float* __restrict__ out, int N) {
  int lane = threadIdx.x & 63;
  int wid = threadIdx.x >> 6;
  int wr = wid >> 1, wc = wid & 1;
  int r0 = blockIdx.x * 64 + wr * 32;
  int c0 = blockIdx.y * 64 + wc * 32;
  if (c0 >= N) return;
  int lr = lane & 15;
  int ko = (lane >> 4) * 8;
  const unsigned short* Ap0 = A + (size_t)(r0 + lr) * K + ko;
  const unsigned short* Ap1 = Ap0 + (size_t)16 * K;
  const unsigned short* Wp0 = W + (size_t)(c0 + lr) * K + ko;
  const unsigned short* Wp1 = Wp0 + (size_t)16 * K;
  f32x4 acc00 = {0, 0, 0, 0}, acc01 = {0, 0, 0, 0};
  f32x4 acc10 = {0, 0, 0, 0}, acc11 = {0, 0, 0, 0};
#pragma unroll
  for (int k = 0; k < K; k += 32) {
    bf16x8 a0 = *(const bf16x8*)(Ap0 + k);
    bf16x8 a1 = *(const bf16x8*)(Ap1 + k);
    bf16x8 b0 = *(const bf16x8*)(Wp0 + k);
    bf16x8 b1 = *(const bf16x8*)(Wp1 + k);
    acc00 = __builtin_amdgcn_mfma_f32_16x16x32_bf16(a0, b0, acc00, 0, 0, 0);
    acc01 = __builtin_amdgcn_mfma_f32_16x16x32_bf16(a0, b1, acc01, 0, 0, 0);
    acc10 = __builtin_amdgcn_mfma_f32_16x16x32_bf16(a1, b0, acc10, 0, 0, 0);
    acc11 = __builtin_amdgcn_mfma_f32_16x16x32_bf16(a1, b1, acc11, 0, 0, 0);
  }
  int cA = c0 + lr, cB = c0 + 16 + lr;
  float bc0 = bias[cA];
  float bc1 = bias[cB];
  int rb = (lane >> 4) * 4;
#pragma unroll
  for (int i = 0; i < 2; ++i) {
    f32x4 aA = i ? acc10 : acc00;
    f32x4 aB = i ? acc11 : acc01;
#pragma unroll
    for (int r = 0; r < 4; ++r) {
      int row = r0 + i * 16 + rb + r;
      out[(size_t)row * N + cA] = aA[r] + bc0 + res[(size_t)row * N + cA];
      out[(size_t)row * N + cB] = aB[r] + bc1 + res[(size_t)row * N + cB];
    }
  }
}

// ------- flash attention: wave-private LDS, barrier-free, KVBLK=64 ------
// Qp: [b*1024+tok][256]; Kc: [bh][g(4)][tok][8]; Vc: [bh][S>>3][d(32)][S&7]
// Each wave stages the FULL 64-token K/V tile into its own 8 KB LDS region
// (T14: load t+1 -> regs, compute t, write regs -> LDS). No __syncthreads in
// the loop, no cross-wave sharing: per-wave LDS ops are in-order so the
// overwrite lands after the reads. K/V are L2-resident (64 KB/head).
__global__ __launch_bounds__(256, 4)
void attn_kernel(const unsigned short* __restrict__ Qp,
                 const unsigned short* __restrict__ Kc,
                 const unsigned short* __restrict__ Vc,
                 unsigned short* __restrict__ O,
                 const float* __restrict__ tau_ptr,
                 float base_scale) {
  __shared__ unsigned short kpriv[4][2048];
  __shared__ unsigned short vpriv[4][2048];
  int lane = threadIdx.x & 63;
  int wid = threadIdx.x >> 6;
  int bh = blockIdx.x;
  int b = bh >> 3, h = bh & 7;
  int q0 = blockIdx.y * 128 + wid * 32;
  float sc = base_scale;
  if (tau_ptr) {
    float lt = tau_ptr[0];
    float sp = (lt > 20.0f) ? lt : log1pf(expf(lt));
    sc /= fminf(sp + 0.5f, 2.0f);
  }
  float scale = sc * 1.4426950408889634f;
  int lr = lane & 15;
  int g = lane >> 4;
  int ko = g * 8;
  int rb = g * 4;
  const size_t tb = (size_t)b * LQN;
  union { bf16x8 v; unsigned short s[8]; unsigned int u[4]; } fq0, fq1;
  fq0.v = *(const bf16x8*)(Qp + (tb + q0 + lr) * 256 + h * 32 + ko);
  fq1.v = *(const bf16x8*)(Qp + (tb + q0 + 16 + lr) * 256 + h * 32 + ko);
#pragma unroll
  for (int j = 0; j < 4; ++j) {
    fq0.u[j] = cvtpk(bf2f(fq0.s[2 * j]) * scale, bf2f(fq0.s[2 * j + 1]) * scale);
    fq1.u[j] = cvtpk(bf2f(fq1.s[2 * j]) * scale, bf2f(fq1.s[2 * j + 1]) * scale);
  }
  bf16x8 aq0 = fq0.v, aq1 = fq1.v;
  const unsigned short* ksrc = Kc + (size_t)bh * 32768;  // 4 planes x 1024 tok x 8
  const unsigned short* vsrc = Vc + (size_t)bh * 32768;
  unsigned short* kw = kpriv[wid];
  unsigned short* vw = vpriv[wid];
  int lo = lane * 8;
  // prologue: tile 0 -> regs -> LDS
  uint4 kr0 = *(const uint4*)(ksrc + lo);
  uint4 kr1 = *(const uint4*)(ksrc + 8192 + lo);
  uint4 kr2 = *(const uint4*)(ksrc + 16384 + lo);
  uint4 kr3 = *(const uint4*)(ksrc + 24576 + lo);
  uint4 vr0 = *(const uint4*)(vsrc + lo);
  uint4 vr1 = *(const uint4*)(vsrc + 512 + lo);
  uint4 vr2 = *(const uint4*)(vsrc + 1024 + lo);
  uint4 vr3 = *(const uint4*)(vsrc + 1536 + lo);
  *(uint4*)(kw + lo) = kr0;
  *(uint4*)(kw + 512 + lo) = kr1;
  *(uint4*)(kw + 1024 + lo) = kr2;
  *(uint4*)(kw + 1536 + lo) = kr3;
  *(uint4*)(vw + lo) = vr0;
  *(uint4*)(vw + 512 + lo) = vr1;
  *(uint4*)(vw + 1024 + lo) = vr2;
  *(uint4*)(vw + 1536 + lo) = vr3;
  f32x4 o00 = {0, 0, 0, 0}, o01 = {0, 0, 0, 0};
  f32x4 o10 = {0, 0, 0, 0}, o11 = {0, 0, 0, 0};
  const f32x4 zero = {0, 0, 0, 0};
#pragma unroll 1
  for (int kt = 0; kt < LKN; kt += 64) {
    int ktn = (kt + 64 < LKN) ? kt + 64 : 0;
    // issue next-tile loads (consumed by the stores at loop end)
    kr0 = *(const uint4*)(ksrc + ktn * 8 + lo);
    kr1 = *(const uint4*)(ksrc + 8192 + ktn * 8 + lo);
    kr2 = *(const uint4*)(ksrc + 16384 + ktn * 8 + lo);
    kr3 = *(const uint4*)(ksrc + 24576 + ktn * 8 + lo);
    vr0 = *(const uint4*)(vsrc + ktn * 32 + lo);
    vr1 = *(const uint4*)(vsrc + ktn * 32 + 512 + lo);
    vr2 = *(const uint4*)(vsrc + ktn * 32 + 1024 + lo);
    vr3 = *(const uint4*)(vsrc + ktn * 32 + 1536 + lo);
    // compute tile kt from private LDS
    bf16x8 ck0 = *(const bf16x8*)(kw + g * 512 + lr * 8);
    bf16x8 ck1 = *(const bf16x8*)(kw + g * 512 + (16 + lr) * 8);
    bf16x8 ck2 = *(const bf16x8*)(kw + g * 512 + (32 + lr) * 8);
    bf16x8 ck3 = *(const bf16x8*)(kw + g * 512 + (48 + lr) * 8);
    __builtin_amdgcn_s_setprio(1);
    f32x4 s0 = __builtin_amdgcn_mfma_f32_16x16x32_bf16(ck0, aq0, zero, 0, 0, 0);
    f32x4 s1 = __builtin_amdgcn_mfma_f32_16x16x32_bf16(ck1, aq0, zero, 0, 0, 0);
    f32x4 s2 = __builtin_amdgcn_mfma_f32_16x16x32_bf16(ck2, aq0, zero, 0, 0, 0);
    f32x4 s3 = __builtin_amdgcn_mfma_f32_16x16x32_bf16(ck3, aq0, zero, 0, 0, 0);
    __builtin_amdgcn_s_setprio(0);
    union { bf16x8 v; unsigned int u[4]; } p1, p2, p3, p4;
    p1.u[0] = cvtpk(ex2(s0[0]), ex2(s0[1]));
    p1.u[1] = cvtpk(ex2(s0[2]), ex2(s0[3]));
    p1.u[2] = cvtpk(ex2(s1[0]), ex2(s1[1]));
    p1.u[3] = cvtpk(ex2(s1[2]), ex2(s1[3]));
    p2.u[0] = cvtpk(ex2(s2[0]), ex2(s2[1]));
    p2.u[1] = cvtpk(ex2(s2[2]), ex2(s2[3]));
    p2.u[2] = cvtpk(ex2(s3[0]), ex2(s3[1]));
    p2.u[3] = cvtpk(ex2(s3[2]), ex2(s3[3]));
    __builtin_amdgcn_s_setprio(1);
    s0 = __builtin_amdgcn_mfma_f32_16x16x32_bf16(ck0, aq1, zero, 0, 0, 0);
    s1 = __builtin_amdgcn_mfma_f32_16x16x32_bf16(ck1, aq1, zero, 0, 0, 0);
    s2 = __builtin_amdgcn_mfma_f32_16x16x32_bf16(ck2, aq1, zero, 0, 0, 0);
    s3 = __builtin_amdgcn_mfma_f32_16x16x32_bf16(ck3, aq1, zero, 0, 0, 0);
    __builtin_amdgcn_s_setprio(0);
    p3.u[0] = cvtpk(ex2(s0[0]), ex2(s0[1]));
    p3.u[1] = cvtpk(ex2(s0[2]), ex2(s0[3]));
    p3.u[2] = cvtpk(ex2(s1[0]), ex2(s1[1]));
    p3.u[3] = cvtpk(ex2(s1[2]), ex2(s1[3]));
    p4.u[0] = cvtpk(ex2(s2[0]), ex2(s2[1]));
    p4.u[1] = cvtpk(ex2(s2[2]), ex2(s2[3]));
    p4.u[2] = cvtpk(ex2(s3[0]), ex2(s3[1]));
    p4.u[3] = cvtpk(ex2(s3[2]), ex2(s3[3]));
    bf16x8 w00 = *(const bf16x8*)(vw + g * 256 + lr * 8);
    bf16x8 w01 = *(const bf16x8*)(vw + (4 + g) * 256 + lr * 8);
    bf16x8 w10 = *(const bf16x8*)(vw + g * 256 + (16 + lr) * 8);
    bf16x8 w11 = *(const bf16x8*)(vw + (4 + g) * 256 + (16 + lr) * 8);
    __builtin_amdgcn_s_setprio(1);
    o00 = __builtin_amdgcn_mfma_f32_16x16x32_bf16(p1.v, w00, o00, 0, 0, 0);
    o00 = __builtin_amdgcn_mfma_f32_16x16x32_bf16(p2.v, w01, o00, 0, 0, 0);
    o01 = __builtin_amdgcn_mfma_f32_16x16x32_bf16(p1.v, w10, o01, 0, 0, 0);
    o01 = __builtin_amdgcn_mfma_f32_16x16x32_bf16(p2.v, w11, o01, 0, 0, 0);
    o10 = __builtin_amdgcn_mfma_f32_16x16x32_bf16(p3.v, w00, o10, 0, 0, 0);
    o10 = __builtin_amdgcn_mfma_f32_16x16x32_bf16(p4.v, w01, o10, 0, 0, 0);
    o11 = __builtin_amdgcn_mfma_f32_16x16x32_bf16(p3.v, w10, o11, 0, 0, 0);
    o11 = __builtin_amdgcn_mfma_f32_16x16x32_bf16(p4.v, w11, o11, 0, 0, 0);
    __builtin_amdgcn_s_setprio(0);
    // write next tile into the same private buffer (in-order after reads)
    *(uint4*)(kw + lo) = kr0;
    *(uint4*)(kw + 512 + lo) = kr1;
    *(uint4*)(kw + 1024 + lo) = kr2;
    *(uint4*)(kw + 1536 + lo) = kr3;
    *(uint4*)(vw + lo) = vr0;
    *(uint4*)(vw + 512 + lo) = vr1;
    *(uint4*)(vw + 1024 + lo) = vr2;
    *(uint4*)(vw + 1536 + lo) = vr3;
  }
  unsigned short* ob = O + (tb + q0) * DM + h * HDIM;
  int psl = (lane & 48) + 4;
#pragma unroll
  for (int r = 0; r < 4; ++r) {
    int qr = rb + r;
    float inv0 = 1.0f / __shfl(o01[r], psl, 64);
    ob[(size_t)qr * DM + lr] = f2bf(o00[r] * inv0);
    if (lr < 4) ob[(size_t)qr * DM + 16 + lr] = f2bf(o01[r] * inv0);
    float inv1 = 1.0f / __shfl(o11[r], psl, 64);
    ob[(size_t)(16 + qr) * DM + lr] = f2bf(o10[r] * inv1);
    if (lr < 4) ob[(size_t)(16 + qr) * DM + 16 + lr] = f2bf(o11[r] * inv1);
  }
}

extern "C" void kernel_launch(void* const* d_in, const int* in_sizes, int n_in,
                              void* d_out, int out_size, void* d_ws, size_t ws_size,
                              hipStream_t stream) {
  (void)in_sizes; (void)n_in; (void)out_size; (void)ws_size;
  const float* q        = (const float*)d_in[0];
  const float* kv       = (const float*)d_in[1];
  const float* ln1_g    = (const float*)d_in[2];
  const float* ln1_b    = (const float*)d_in[3];
  const float* sa_in_w  = (const float*)d_in[4];
  const float* sa_in_b  = (const float*)d_in[5];
  const float* sa_out_w = (const float*)d_in[6];
  const float* sa_out_b = (const float*)d_in[7];
  const float* ln2_g    = (const float*)d_in[8];
  const float* ln2_b    = (const float*)d_in[9];
  const float* lnkv_g   = (const float*)d_in[10];
  const float* lnkv_b   = (const float*)d_in[11];
  const float* ca_qw    = (const float*)d_in[12];
  const float* ca_qb    = (const float*)d_in[13];
  const float* ca_kw    = (const float*)d_in[14];
  const float* ca_kb    = (const float*)d_in[15];
  const float* ca_vw    = (const float*)d_in[16];
  const float* ca_vb    = (const float*)d_in[17];
  const float* ca_ow    = (const float*)d_in[18];
  const float* ca_ob    = (const float*)d_in[19];
  const float* log_tau  = (const float*)d_in[20];
  const float* lnf_g    = (const float*)d_in[21];
  const float* lnf_b    = (const float*)d_in[22];
  const float* w1       = (const float*)d_in[23];
  const float* b1       = (const float*)d_in[24];
  const float* w2       = (const float*)d_in[25];
  const float* b2       = (const float*)d_in[26];

  const int M = NB * LQN;  // 16384 rows
  char* ws = (char*)d_ws;
  unsigned short* wb   = (unsigned short*)(ws);
  float*          bcat = (float*)(ws + 860160);
  unsigned short* qn   = (unsigned short*)(ws + 1048576);
  unsigned short* sqp  = (unsigned short*)(ws + 6291456);
  unsigned short* skc  = (unsigned short*)(ws + 14680064);
  unsigned short* svc  = (unsigned short*)(ws + 23068672);
  unsigned short* attn = (unsigned short*)(ws + 31457280);
  unsigned short* kvn  = (unsigned short*)(ws + 36700160);
  float*          q1   = (float*)(ws + 41943040);
  float*          q2   = (float*)(ws + 52428800);
  unsigned short* hbuf = (unsigned short*)(ws + 6291456);  // FFN phase reuse

  unsigned short* b_sa_in  = wb;            // 76800 (Q|K|V contiguous)
  unsigned short* b_sa_out = wb + 76800;    // 25600
  unsigned short* b_ca_q   = wb + 102400;   // 25600 (q|k|v contiguous)
  unsigned short* b_ca_o   = wb + 179200;   // 25600
  unsigned short* b_w1     = wb + 204800;   // 102400
  unsigned short* b_w2     = wb + 307200;   // 102400

  dim3 blk(256);
  const float isq = 0.22360679774997896f;  // 1/sqrt(20)

  CvtArgs ca;
  ca.src[0] = sa_in_w;  ca.src[1] = sa_out_w; ca.src[2] = ca_qw; ca.src[3] = ca_kw;
  ca.src[4] = ca_vw;    ca.src[5] = ca_ow;    ca.src[6] = w1;    ca.src[7] = w2;
  int cum[9] = {0, 76800, 102400, 128000, 153600, 179200, 204800, 307200, 409600};
  for (int i = 0; i < 9; ++i) ca.cum[i] = cum[i];
  init_kernel<<<dim3(M / 2), blk, 0, stream>>>(
      (uint4*)(ws + 6291456), 1048576, (uint4*)(ws + 23068672), 524288,
      ca_qb, ca_kb, ca_vb, bcat, ca, wb,
      q, ln1_g, ln1_b, qn, kv, lnkv_g, lnkv_b, kvn, M);

  // --- self attention block ---
  gemm160_kernel<0, 10><<<dim3(M / 64, 3), blk, 0, stream>>>(
      qn, qn, b_sa_in, sa_in_b, nullptr, sqp, skc, svc, nullptr, nullptr);
  attn_kernel<<<dim3(NB * NHEADS, LQN / 128), blk, 0, stream>>>(sqp, skc, svc, attn, nullptr, isq);
  gemm160_kernel<3, 10><<<dim3(M / 64, 1), blk, 0, stream>>>(
      attn, attn, b_sa_out, sa_out_b, q, q1, qn, nullptr, ln2_g, ln2_b);

  // --- cross attention block ---
  gemm160_kernel<0, 10><<<dim3(M / 64, 3), blk, 0, stream>>>(
      qn, kvn, b_ca_q, bcat, nullptr, sqp, skc, svc, nullptr, nullptr);
  attn_kernel<<<dim3(NB * NHEADS, LQN / 128), blk, 0, stream>>>(sqp, skc, svc, attn, log_tau, isq);
  gemm160_kernel<3, 10><<<dim3(M / 64, 1), blk, 0, stream>>>(
      attn, attn, b_ca_o, ca_ob, q1, q2, qn, nullptr, lnf_g, lnf_b);

  // --- FFN ---
  gemm160_kernel<2, 10><<<dim3(M / 64, 4), blk, 0, stream>>>(
      qn, qn, b_w1, b1, nullptr, hbuf, nullptr, nullptr, nullptr, nullptr);
  gemm_kernel<640><<<dim3(M / 64, 3), blk, 0, stream>>>(hbuf, b_w2, b2, q2, (float*)d_out, 160);
}

// Round 16
// 170.536 us; speedup vs baseline: 1.0146x; 1.0146x over previous
//
#include <hip/hip_runtime.h>
#include <hip/hip_bf16.h>
#include <math.h>

#define LQN 1024
#define LKN 1024
#define NB 16
#define DM 160
#define NHEADS 8
#define HDIM 20

typedef __attribute__((ext_vector_type(8))) short bf16x8;
typedef __attribute__((ext_vector_type(4))) float f32x4;

__device__ __forceinline__ float bf2f(unsigned short h) {
  union { unsigned int u; float f; } c; c.u = ((unsigned int)h) << 16; return c.f;
}
__device__ __forceinline__ unsigned short f2bf(float f) {
  union { float f; unsigned int u; } c; c.f = f;
  unsigned int lsb = (c.u >> 16) & 1u;
  unsigned int r = c.u + 0x7fffu + lsb;
  return (unsigned short)(r >> 16);
}
__device__ __forceinline__ unsigned int cvtpk(float a, float b) {
  unsigned int r;
  asm("v_cvt_pk_bf16_f32 %0, %1, %2" : "=v"(r) : "v"(a), "v"(b));
  return r;
}
__device__ __forceinline__ float ex2(float x) { return __builtin_amdgcn_exp2f(x); }

struct CvtArgs {
  const float* src[8];
  int cum[9];
};

// ---- fused init + dual input LayerNorm ----
__global__ void init_kernel(uint4* __restrict__ zbase, int nz,
                            uint4* __restrict__ vbase, int nv,
                            const float* __restrict__ b0,
                            const float* __restrict__ b1,
                            const float* __restrict__ b2,
                            float* __restrict__ bcat,
                            CvtArgs a, unsigned short* __restrict__ wdst,
                            const float* __restrict__ x1,
                            const float* __restrict__ g1,
                            const float* __restrict__ bb1,
                            unsigned short* __restrict__ y1,
                            const float* __restrict__ x2,
                            const float* __restrict__ g2,
                            const float* __restrict__ bb2,
                            unsigned short* __restrict__ y2, int rowsPer) {
  int i = blockIdx.x * 256 + threadIdx.x;
  if (i < nz) zbase[i] = make_uint4(0, 0, 0, 0);
  if (i < nv) {
    unsigned int v = ((i & 31) == 20) ? 0x3F803F80u : 0u;
    vbase[i] = make_uint4(v, v, v, v);
  }
  if (i < 480) bcat[i] = (i < 160) ? b0[i] : (i < 320 ? b1[i - 160] : b2[i - 320]);
  if (i < 409600) {
    int s = 0;
#pragma unroll
    for (int t = 0; t < 7; ++t) s += (i >= a.cum[t + 1]) ? 1 : 0;
    wdst[i] = f2bf(a.src[s][i - a.cum[s]]);
  }
  int row = blockIdx.x * 4 + (threadIdx.x >> 6);
  int lane = threadIdx.x & 63;
  const float* x; const float* g; const float* b; unsigned short* y;
  if (row < rowsPer) {
    x = x1 + (size_t)row * DM; g = g1; b = bb1; y = y1 + (size_t)row * DM;
  } else {
    int r2 = row - rowsPer;
    x = x2 + (size_t)r2 * DM; g = g2; b = bb2; y = y2 + (size_t)r2 * DM;
  }
  float a0 = x[lane];
  float a1 = x[lane + 64];
  float a2 = (lane < 32) ? x[lane + 128] : 0.0f;
  float s = a0 + a1 + a2;
#pragma unroll
  for (int m = 1; m < 64; m <<= 1) s += __shfl_xor(s, m);
  float mean = s * (1.0f / DM);
  float d0 = a0 - mean, d1 = a1 - mean, d2 = a2 - mean;
  float vs = d0 * d0 + d1 * d1 + ((lane < 32) ? d2 * d2 : 0.0f);
#pragma unroll
  for (int m = 1; m < 64; m <<= 1) vs += __shfl_xor(vs, m);
  float rstd = rsqrtf(vs * (1.0f / DM) + 1e-5f);
  y[lane]      = f2bf(d0 * rstd * g[lane]      + b[lane]);
  y[lane + 64] = f2bf(d1 * rstd * g[lane + 64] + b[lane + 64]);
  if (lane < 32)
    y[lane + 128] = f2bf(d2 * rstd * g[lane + 128] + b[lane + 128]);
}

// ============ LDS-W GEMM: WAVES*16 rows x NCOL*16 cols per block, K=160 =====
// EPI 0 (WAVES=4): qkv (y=0 Q padded / y=1 K chunked / y=2 V slot-chunked)
// EPI 2 (WAVES=4): bias+gelu -> bf16 [row][640] at col offset y*160
// EPI 3 (WAVES=2): bias+res -> f32 [row][160] AND fused LayerNorm -> bf16 Kc
template <int EPI, int NCOL, int WAVES>
__global__ __launch_bounds__(WAVES * 64, 2)
void gemm160_kernel(const unsigned short* __restrict__ Aq,
                    const unsigned short* __restrict__ Akv,
                    const unsigned short* __restrict__ W,
                    const float* __restrict__ bias,
                    const float* __restrict__ res,
                    void* __restrict__ outp,
                    unsigned short* __restrict__ Kc,
                    unsigned short* __restrict__ Vc,
                    const float* __restrict__ lng,
                    const float* __restrict__ lnb) {
  __shared__ unsigned short wl[NCOL * 16 * 168];
  int tid = threadIdx.x;
  int lane = tid & 63;
  int w = tid >> 6;
  int y = blockIdx.y;
  const unsigned short* Wb = W + y * (NCOL * 2560);
  for (int idx = tid * 8; idx < NCOL * 2560; idx += WAVES * 512) {
    int col = idx / 160, k = idx % 160;
    *(uint4*)(wl + col * 168 + k) = *(const uint4*)(Wb + idx);
  }
  __syncthreads();
  int lr = lane & 15;
  int g = lane >> 4;
  int R0 = blockIdx.x * (WAVES * 16);
  int rbase = R0 + w * 16;
  const unsigned short* A = (EPI == 0 && y > 0) ? Akv : Aq;
  const unsigned short* Ap = A + (size_t)(rbase + lr) * 160 + g * 8;
  const unsigned short* wp = wl + lr * 168 + g * 8;
  f32x4 acc[NCOL];
#pragma unroll
  for (int c = 0; c < NCOL; ++c) acc[c] = (f32x4){0, 0, 0, 0};
#pragma unroll
  for (int k0 = 0; k0 < 160; k0 += 32) {
    bf16x8 a = *(const bf16x8*)(Ap + k0);
#pragma unroll
    for (int c = 0; c < NCOL; ++c) {
      bf16x8 bfr = *(const bf16x8*)(wp + c * 16 * 168 + k0);
      acc[c] = __builtin_amdgcn_mfma_f32_16x16x32_bf16(a, bfr, acc[c], 0, 0, 0);
    }
  }
  if (EPI == 0) {
    if (y == 0) {
      unsigned short* Qp = (unsigned short*)outp;
#pragma unroll
      for (int c = 0; c < NCOL; ++c) {
        int col = c * 16 + lr;
        int h = col / 20, d = col % 20;
        float bc = bias[col];
#pragma unroll
        for (int r = 0; r < 4; ++r) {
          int row = rbase + g * 4 + r;
          Qp[(size_t)row * 256 + h * 32 + d] = f2bf(acc[c][r] + bc);
        }
      }
    } else if (y == 1) {
      int b = R0 >> 10;
#pragma unroll
      for (int c = 0; c < NCOL; ++c) {
        int col = c * 16 + lr;
        int h = col / 20, d = col % 20;
        float bc = bias[160 + col];
        size_t base = ((((size_t)(b * 8 + h)) * 4 + (d >> 3)) * 1024) * 8 + (d & 7);
#pragma unroll
        for (int r = 0; r < 4; ++r) {
          int tok = (rbase + g * 4 + r) & 1023;
          Kc[base + (size_t)tok * 8] = f2bf(acc[c][r] + bc);
        }
      }
    } else {
      int b = R0 >> 10;
      int base64 = R0 & 1023;
      int slotbase = base64 + g * 8 + (w & 1) * 4 + (w >> 1) * 32;
#pragma unroll
      for (int c = 0; c < NCOL; ++c) {
        int col = c * 16 + lr;
        int h = col / 20, d = col % 20;
        float bc = bias[320 + col];
        size_t vb = ((size_t)(b * 8 + h) * 128) * 256 + (size_t)d * 8;
#pragma unroll
        for (int r = 0; r < 4; ++r) {
          int S = slotbase + r;
          Vc[vb + (size_t)(S >> 3) * 256 + (S & 7)] = f2bf(acc[c][r] + bc);
        }
      }
    }
  } else if (EPI == 2) {
    unsigned short* out = (unsigned short*)outp;
#pragma unroll
    for (int c = 0; c < NCOL; ++c) {
      int colg = y * NCOL * 16 + c * 16 + lr;
      float bc = bias[colg];
#pragma unroll
      for (int r = 0; r < 4; ++r) {
        int row = rbase + g * 4 + r;
        float v = acc[c][r] + bc;
        v = 0.5f * v * (1.0f + erff(v * 0.70710678118654752f));
        out[(size_t)row * 640 + colg] = f2bf(v);
      }
    }
  } else {
    float* out = (float*)outp;
#pragma unroll
    for (int c = 0; c < NCOL; ++c) {
      int col = c * 16 + lr;
      float bc = bias[col];
#pragma unroll
      for (int r = 0; r < 4; ++r) {
        int row = rbase + g * 4 + r;
        float v = acc[c][r] + bc + res[(size_t)row * 160 + col];
        acc[c][r] = v;
        out[(size_t)row * 160 + col] = v;
      }
    }
#pragma unroll
    for (int r = 0; r < 4; ++r) {
      float s = 0.0f, sq = 0.0f;
#pragma unroll
      for (int c = 0; c < NCOL; ++c) { s += acc[c][r]; sq += acc[c][r] * acc[c][r]; }
#pragma unroll
      for (int m = 1; m < 16; m <<= 1) { s += __shfl_xor(s, m); sq += __shfl_xor(sq, m); }
      float mean = s * (1.0f / DM);
      float var = sq * (1.0f / DM) - mean * mean;
      float rstd = rsqrtf(var + 1e-5f);
      int row = rbase + g * 4 + r;
#pragma unroll
      for (int c = 0; c < NCOL; ++c) {
        int col = c * 16 + lr;
        Kc[(size_t)row * 160 + col] =
            f2bf((acc[c][r] - mean) * rstd * lng[col] + lnb[col]);
      }
    }
  }
}

// ---------------- old-style GEMM for w2 (K=640) ----------------
template <int K>
__global__ __launch_bounds__(256, 4)
void gemm_kernel(const unsigned short* __restrict__ A,
                 const unsigned short* __restrict__ W,
                 const float* __restrict__ bias,
                 const float* __restrict__ res,
                 float* __restrict__ out, int N) {
  int lane = threadIdx.x & 63;
  int wid = threadIdx.x >> 6;
  int wr = wid >> 1, wc = wid & 1;
  int r0 = blockIdx.x * 64 + wr * 32;
  int c0 = blockIdx.y * 64 + wc * 32;
  if (c0 >= N) return;
  int lr = lane & 15;
  int ko = (lane >> 4) * 8;
  const unsigned short* Ap0 = A + (size_t)(r0 + lr) * K + ko;
  const unsigned short* Ap1 = Ap0 + (size_t)16 * K;
  const unsigned short* Wp0 = W + (size_t)(c0 + lr) * K + ko;
  const unsigned short* Wp1 = Wp0 + (size_t)16 * K;
  f32x4 acc00 = {0, 0, 0, 0}, acc01 = {0, 0, 0, 0};
  f32x4 acc10 = {0, 0, 0, 0}, acc11 = {0, 0, 0, 0};
#pragma unroll
  for (int k = 0; k < K; k += 32) {
    bf16x8 a0 = *(const bf16x8*)(Ap0 + k);
    bf16x8 a1 = *(const bf16x8*)(Ap1 + k);
    bf16x8 b0 = *(const bf16x8*)(Wp0 + k);
    bf16x8 b1 = *(const bf16x8*)(Wp1 + k);
    acc00 = __builtin_amdgcn_mfma_f32_16x16x32_bf16(a0, b0, acc00, 0, 0, 0);
    acc01 = __builtin_amdgcn_mfma_f32_16x16x32_bf16(a0, b1, acc01, 0, 0, 0);
    acc10 = __builtin_amdgcn_mfma_f32_16x16x32_bf16(a1, b0, acc10, 0, 0, 0);
    acc11 = __builtin_amdgcn_mfma_f32_16x16x32_bf16(a1, b1, acc11, 0, 0, 0);
  }
  int cA = c0 + lr, cB = c0 + 16 + lr;
  float bc0 = bias[cA];
  float bc1 = bias[cB];
  int rb = (lane >> 4) * 4;
#pragma unroll
  for (int i = 0; i < 2; ++i) {
    f32x4 aA = i ? acc10 : acc00;
    f32x4 aB = i ? acc11 : acc01;
#pragma unroll
    for (int r = 0; r < 4; ++r) {
      int row = r0 + i * 16 + rb + r;
      out[(size_t)row * N + cA] = aA[r] + bc0 + res[(size_t)row * N + cA];
      out[(size_t)row * N + cB] = aB[r] + bc1 + res[(size_t)row * N + cB];
    }
  }
}

// ------- flash attention: swapped QK^T, in-register P, KVBLK=128 ------
// (round-14 verified version: shared double-buffer + __syncthreads + setprio)
__global__ __launch_bounds__(256, 4)
void attn_kernel(const unsigned short* __restrict__ Qp,
                 const unsigned short* __restrict__ Kc,
                 const unsigned short* __restrict__ Vc,
                 unsigned short* __restrict__ O,
                 const float* __restrict__ tau_ptr,
                 float base_scale) {
  __shared__ unsigned short kbuf[2][4096];
  __shared__ unsigned short vbuf[2][4096];
  int lane = threadIdx.x & 63;
  int wid = threadIdx.x >> 6;
  int bh = blockIdx.x;
  int b = bh >> 3, h = bh & 7;
  int q0 = blockIdx.y * 128 + wid * 32;
  float sc = base_scale;
  if (tau_ptr) {
    float lt = tau_ptr[0];
    float sp = (lt > 20.0f) ? lt : log1pf(expf(lt));
    sc /= fminf(sp + 0.5f, 2.0f);
  }
  float scale = sc * 1.4426950408889634f;
  int lr = lane & 15;
  int g = lane >> 4;
  int ko = g * 8;
  int rb = g * 4;
  const size_t tb = (size_t)b * LQN;
  union { bf16x8 v; unsigned short s[8]; unsigned int u[4]; } fq0, fq1;
  fq0.v = *(const bf16x8*)(Qp + (tb + q0 + lr) * 256 + h * 32 + ko);
  fq1.v = *(const bf16x8*)(Qp + (tb + q0 + 16 + lr) * 256 + h * 32 + ko);
#pragma unroll
  for (int j = 0; j < 4; ++j) {
    fq0.u[j] = cvtpk(bf2f(fq0.s[2 * j]) * scale, bf2f(fq0.s[2 * j + 1]) * scale);
    fq1.u[j] = cvtpk(bf2f(fq1.s[2 * j]) * scale, bf2f(fq1.s[2 * j + 1]) * scale);
  }
  bf16x8 aq0 = fq0.v, aq1 = fq1.v;
  const unsigned short* ksrc = Kc + (((size_t)bh * 4 + wid) * 1024) * 8;
  const unsigned short* vsrc = Vc + (size_t)bh * 32768;
  int sd = wid * 1024 + lane * 8;
  {
    uint4 k0 = *(const uint4*)(ksrc + lane * 8);
    uint4 k1 = *(const uint4*)(ksrc + (64 + lane) * 8);
    uint4 v0 = *(const uint4*)(vsrc + sd);
    uint4 v1 = *(const uint4*)(vsrc + sd + 512);
    *(uint4*)(kbuf[0] + sd) = k0;
    *(uint4*)(kbuf[0] + sd + 512) = k1;
    *(uint4*)(vbuf[0] + sd) = v0;
    *(uint4*)(vbuf[0] + sd + 512) = v1;
  }
  __syncthreads();
  int cur = 0;
  f32x4 o00 = {0, 0, 0, 0}, o01 = {0, 0, 0, 0};
  f32x4 o10 = {0, 0, 0, 0}, o11 = {0, 0, 0, 0};
  const f32x4 zero = {0, 0, 0, 0};

#define ATTN_COMPUTE(KB, VB)                                                   \
  {                                                                            \
    const unsigned short* kp_ = (KB);                                          \
    const unsigned short* vp_ = (VB);                                          \
    bf16x8 ck0 = *(const bf16x8*)(kp_ + g * 1024 + lr * 8);                    \
    bf16x8 ck1 = *(const bf16x8*)(kp_ + g * 1024 + (16 + lr) * 8);             \
    bf16x8 ck2 = *(const bf16x8*)(kp_ + g * 1024 + (32 + lr) * 8);             \
    bf16x8 ck3 = *(const bf16x8*)(kp_ + g * 1024 + (48 + lr) * 8);             \
    __builtin_amdgcn_s_setprio(1);                                             \
    f32x4 s0 = __builtin_amdgcn_mfma_f32_16x16x32_bf16(ck0, aq0, zero, 0, 0, 0);\
    f32x4 s1 = __builtin_amdgcn_mfma_f32_16x16x32_bf16(ck1, aq0, zero, 0, 0, 0);\
    f32x4 s2 = __builtin_amdgcn_mfma_f32_16x16x32_bf16(ck2, aq0, zero, 0, 0, 0);\
    f32x4 s3 = __builtin_amdgcn_mfma_f32_16x16x32_bf16(ck3, aq0, zero, 0, 0, 0);\
    __builtin_amdgcn_s_setprio(0);                                             \
    union { bf16x8 v; unsigned int u[4]; } p1, p2, p3, p4;                     \
    p1.u[0] = cvtpk(ex2(s0[0]), ex2(s0[1]));                                   \
    p1.u[1] = cvtpk(ex2(s0[2]), ex2(s0[3]));                                   \
    p1.u[2] = cvtpk(ex2(s1[0]), ex2(s1[1]));                                   \
    p1.u[3] = cvtpk(ex2(s1[2]), ex2(s1[3]));                                   \
    p2.u[0] = cvtpk(ex2(s2[0]), ex2(s2[1]));                                   \
    p2.u[1] = cvtpk(ex2(s2[2]), ex2(s2[3]));                                   \
    p2.u[2] = cvtpk(ex2(s3[0]), ex2(s3[1]));                                   \
    p2.u[3] = cvtpk(ex2(s3[2]), ex2(s3[3]));                                   \
    __builtin_amdgcn_s_setprio(1);                                             \
    s0 = __builtin_amdgcn_mfma_f32_16x16x32_bf16(ck0, aq1, zero, 0, 0, 0);     \
    s1 = __builtin_amdgcn_mfma_f32_16x16x32_bf16(ck1, aq1, zero, 0, 0, 0);     \
    s2 = __builtin_amdgcn_mfma_f32_16x16x32_bf16(ck2, aq1, zero, 0, 0, 0);     \
    s3 = __builtin_amdgcn_mfma_f32_16x16x32_bf16(ck3, aq1, zero, 0, 0, 0);     \
    __builtin_amdgcn_s_setprio(0);                                             \
    p3.u[0] = cvtpk(ex2(s0[0]), ex2(s0[1]));                                   \
    p3.u[1] = cvtpk(ex2(s0[2]), ex2(s0[3]));                                   \
    p3.u[2] = cvtpk(ex2(s1[0]), ex2(s1[1]));                                   \
    p3.u[3] = cvtpk(ex2(s1[2]), ex2(s1[3]));                                   \
    p4.u[0] = cvtpk(ex2(s2[0]), ex2(s2[1]));                                   \
    p4.u[1] = cvtpk(ex2(s2[2]), ex2(s2[3]));                                   \
    p4.u[2] = cvtpk(ex2(s3[0]), ex2(s3[1]));                                   \
    p4.u[3] = cvtpk(ex2(s3[2]), ex2(s3[3]));                                   \
    bf16x8 w00 = *(const bf16x8*)(vp_ + g * 256 + lr * 8);                     \
    bf16x8 w01 = *(const bf16x8*)(vp_ + (4 + g) * 256 + lr * 8);               \
    bf16x8 w10 = *(const bf16x8*)(vp_ + g * 256 + (16 + lr) * 8);              \
    bf16x8 w11 = *(const bf16x8*)(vp_ + (4 + g) * 256 + (16 + lr) * 8);        \
    __builtin_amdgcn_s_setprio(1);                                             \
    o00 = __builtin_amdgcn_mfma_f32_16x16x32_bf16(p1.v, w00, o00, 0, 0, 0);    \
    o00 = __builtin_amdgcn_mfma_f32_16x16x32_bf16(p2.v, w01, o00, 0, 0, 0);    \
    o01 = __builtin_amdgcn_mfma_f32_16x16x32_bf16(p1.v, w10, o01, 0, 0, 0);    \
    o01 = __builtin_amdgcn_mfma_f32_16x16x32_bf16(p2.v, w11, o01, 0, 0, 0);    \
    o10 = __builtin_amdgcn_mfma_f32_16x16x32_bf16(p3.v, w00, o10, 0, 0, 0);    \
    o10 = __builtin_amdgcn_mfma_f32_16x16x32_bf16(p4.v, w01, o10, 0, 0, 0);    \
    o11 = __builtin_amdgcn_mfma_f32_16x16x32_bf16(p3.v, w10, o11, 0, 0, 0);    \
    o11 = __builtin_amdgcn_mfma_f32_16x16x32_bf16(p4.v, w11, o11, 0, 0, 0);    \
    __builtin_amdgcn_s_setprio(0);                                             \
  }

#pragma unroll 1
  for (int kt = 0; kt < LKN; kt += 128) {
    int ktn = (kt + 128 < LKN) ? kt + 128 : 0;
    uint4 kA0 = *(const uint4*)(ksrc + (ktn + lane) * 8);
    uint4 kA1 = *(const uint4*)(ksrc + (ktn + 64 + lane) * 8);
    uint4 vA0 = *(const uint4*)(vsrc + ktn * 32 + sd);
    uint4 vA1 = *(const uint4*)(vsrc + ktn * 32 + sd + 512);
    ATTN_COMPUTE(kbuf[cur], vbuf[cur])
    *(uint4*)(kbuf[cur ^ 1] + sd) = kA0;
    *(uint4*)(kbuf[cur ^ 1] + sd + 512) = kA1;
    ATTN_COMPUTE(kbuf[cur] + 512, vbuf[cur] + 2048)
    *(uint4*)(vbuf[cur ^ 1] + sd) = vA0;
    *(uint4*)(vbuf[cur ^ 1] + sd + 512) = vA1;
    __syncthreads();
    cur ^= 1;
  }
#undef ATTN_COMPUTE
  unsigned short* ob = O + (tb + q0) * DM + h * HDIM;
  int psl = (lane & 48) + 4;
#pragma unroll
  for (int r = 0; r < 4; ++r) {
    int qr = rb + r;
    float inv0 = 1.0f / __shfl(o01[r], psl, 64);
    ob[(size_t)qr * DM + lr] = f2bf(o00[r] * inv0);
    if (lr < 4) ob[(size_t)qr * DM + 16 + lr] = f2bf(o01[r] * inv0);
    float inv1 = 1.0f / __shfl(o11[r], psl, 64);
    ob[(size_t)(16 + qr) * DM + lr] = f2bf(o10[r] * inv1);
    if (lr < 4) ob[(size_t)(16 + qr) * DM + 16 + lr] = f2bf(o11[r] * inv1);
  }
}

extern "C" void kernel_launch(void* const* d_in, const int* in_sizes, int n_in,
                              void* d_out, int out_size, void* d_ws, size_t ws_size,
                              hipStream_t stream) {
  (void)in_sizes; (void)n_in; (void)out_size; (void)ws_size;
  const float* q        = (const float*)d_in[0];
  const float* kv       = (const float*)d_in[1];
  const float* ln1_g    = (const float*)d_in[2];
  const float* ln1_b    = (const float*)d_in[3];
  const float* sa_in_w  = (const float*)d_in[4];
  const float* sa_in_b  = (const float*)d_in[5];
  const float* sa_out_w = (const float*)d_in[6];
  const float* sa_out_b = (const float*)d_in[7];
  const float* ln2_g    = (const float*)d_in[8];
  const float* ln2_b    = (const float*)d_in[9];
  const float* lnkv_g   = (const float*)d_in[10];
  const float* lnkv_b   = (const float*)d_in[11];
  const float* ca_qw    = (const float*)d_in[12];
  const float* ca_qb    = (const float*)d_in[13];
  const float* ca_kw    = (const float*)d_in[14];
  const float* ca_kb    = (const float*)d_in[15];
  const float* ca_vw    = (const float*)d_in[16];
  const float* ca_vb    = (const float*)d_in[17];
  const float* ca_ow    = (const float*)d_in[18];
  const float* ca_ob    = (const float*)d_in[19];
  const float* log_tau  = (const float*)d_in[20];
  const float* lnf_g    = (const float*)d_in[21];
  const float* lnf_b    = (const float*)d_in[22];
  const float* w1       = (const float*)d_in[23];
  const float* b1       = (const float*)d_in[24];
  const float* w2       = (const float*)d_in[25];
  const float* b2       = (const float*)d_in[26];

  const int M = NB * LQN;  // 16384 rows
  char* ws = (char*)d_ws;
  unsigned short* wb   = (unsigned short*)(ws);
  float*          bcat = (float*)(ws + 860160);
  unsigned short* qn   = (unsigned short*)(ws + 1048576);
  unsigned short* sqp  = (unsigned short*)(ws + 6291456);
  unsigned short* skc  = (unsigned short*)(ws + 14680064);
  unsigned short* svc  = (unsigned short*)(ws + 23068672);
  unsigned short* attn = (unsigned short*)(ws + 31457280);
  unsigned short* kvn  = (unsigned short*)(ws + 36700160);
  float*          q1   = (float*)(ws + 41943040);
  float*          q2   = (float*)(ws + 52428800);
  unsigned short* hbuf = (unsigned short*)(ws + 6291456);  // FFN phase reuse

  unsigned short* b_sa_in  = wb;            // 76800 (Q|K|V contiguous)
  unsigned short* b_sa_out = wb + 76800;    // 25600
  unsigned short* b_ca_q   = wb + 102400;   // 25600 (q|k|v contiguous)
  unsigned short* b_ca_o   = wb + 179200;   // 25600
  unsigned short* b_w1     = wb + 204800;   // 102400
  unsigned short* b_w2     = wb + 307200;   // 102400

  dim3 blk(256);
  const float isq = 0.22360679774997896f;  // 1/sqrt(20)

  CvtArgs ca;
  ca.src[0] = sa_in_w;  ca.src[1] = sa_out_w; ca.src[2] = ca_qw; ca.src[3] = ca_kw;
  ca.src[4] = ca_vw;    ca.src[5] = ca_ow;    ca.src[6] = w1;    ca.src[7] = w2;
  int cum[9] = {0, 76800, 102400, 128000, 153600, 179200, 204800, 307200, 409600};
  for (int i = 0; i < 9; ++i) ca.cum[i] = cum[i];
  init_kernel<<<dim3(M / 2), blk, 0, stream>>>(
      (uint4*)(ws + 6291456), 1048576, (uint4*)(ws + 23068672), 524288,
      ca_qb, ca_kb, ca_vb, bcat, ca, wb,
      q, ln1_g, ln1_b, qn, kv, lnkv_g, lnkv_b, kvn, M);

  // --- self attention block ---
  gemm160_kernel<0, 10, 4><<<dim3(M / 64, 3), blk, 0, stream>>>(
      qn, qn, b_sa_in, sa_in_b, nullptr, sqp, skc, svc, nullptr, nullptr);
  attn_kernel<<<dim3(NB * NHEADS, LQN / 128), blk, 0, stream>>>(sqp, skc, svc, attn, nullptr, isq);
  // out-proj+LN: 2-wave blocks (32 rows) -> 512 blocks = 2/CU, W-stage overlaps
  gemm160_kernel<3, 10, 2><<<dim3(M / 32, 1), dim3(128), 0, stream>>>(
      attn, attn, b_sa_out, sa_out_b, q, q1, qn, nullptr, ln2_g, ln2_b);

  // --- cross attention block ---
  gemm160_kernel<0, 10, 4><<<dim3(M / 64, 3), blk, 0, stream>>>(
      qn, kvn, b_ca_q, bcat, nullptr, sqp, skc, svc, nullptr, nullptr);
  attn_kernel<<<dim3(NB * NHEADS, LQN / 128), blk, 0, stream>>>(sqp, skc, svc, attn, log_tau, isq);
  gemm160_kernel<3, 10, 2><<<dim3(M / 32, 1), dim3(128), 0, stream>>>(
      attn, attn, b_ca_o, ca_ob, q1, q2, qn, nullptr, lnf_g, lnf_b);

  // --- FFN ---
  gemm160_kernel<2, 10, 4><<<dim3(M / 64, 4), blk, 0, stream>>>(
      qn, qn, b_w1, b1, nullptr, hbuf, nullptr, nullptr, nullptr, nullptr);
  gemm_kernel<640><<<dim3(M / 64, 3), blk, 0, stream>>>(hbuf, b_w2, b2, q2, (float*)d_out, 160);
}

// Round 17
// 163.419 us; speedup vs baseline: 1.0588x; 1.0435x over previous
//
#include <hip/hip_runtime.h>
#include <hip/hip_bf16.h>
#include <math.h>

#define LQN 1024
#define LKN 1024
#define NB 16
#define DM 160
#define NHEADS 8
#define HDIM 20

typedef __attribute__((ext_vector_type(8))) short bf16x8;
typedef __attribute__((ext_vector_type(4))) float f32x4;

__device__ __forceinline__ float bf2f(unsigned short h) {
  union { unsigned int u; float f; } c; c.u = ((unsigned int)h) << 16; return c.f;
}
__device__ __forceinline__ unsigned short f2bf(float f) {
  union { float f; unsigned int u; } c; c.f = f;
  unsigned int lsb = (c.u >> 16) & 1u;
  unsigned int r = c.u + 0x7fffu + lsb;
  return (unsigned short)(r >> 16);
}
__device__ __forceinline__ unsigned int cvtpk(float a, float b) {
  unsigned int r;
  asm("v_cvt_pk_bf16_f32 %0, %1, %2" : "=v"(r) : "v"(a), "v"(b));
  return r;
}
__device__ __forceinline__ float ex2(float x) { return __builtin_amdgcn_exp2f(x); }

struct CvtArgs {
  const float* src[8];
  int cum[9];
};

// ---- fused init + dual input LayerNorm ----
__global__ void init_kernel(uint4* __restrict__ zbase, int nz,
                            uint4* __restrict__ vbase, int nv,
                            const float* __restrict__ b0,
                            const float* __restrict__ b1,
                            const float* __restrict__ b2,
                            float* __restrict__ bcat,
                            CvtArgs a, unsigned short* __restrict__ wdst,
                            const float* __restrict__ x1,
                            const float* __restrict__ g1,
                            const float* __restrict__ bb1,
                            unsigned short* __restrict__ y1,
                            const float* __restrict__ x2,
                            const float* __restrict__ g2,
                            const float* __restrict__ bb2,
                            unsigned short* __restrict__ y2, int rowsPer) {
  int i = blockIdx.x * 256 + threadIdx.x;
  if (i < nz) zbase[i] = make_uint4(0, 0, 0, 0);
  if (i < nv) {
    unsigned int v = ((i & 31) == 20) ? 0x3F803F80u : 0u;
    vbase[i] = make_uint4(v, v, v, v);
  }
  if (i < 480) bcat[i] = (i < 160) ? b0[i] : (i < 320 ? b1[i - 160] : b2[i - 320]);
  if (i < 409600) {
    int s = 0;
#pragma unroll
    for (int t = 0; t < 7; ++t) s += (i >= a.cum[t + 1]) ? 1 : 0;
    wdst[i] = f2bf(a.src[s][i - a.cum[s]]);
  }
  int row = blockIdx.x * 4 + (threadIdx.x >> 6);
  int lane = threadIdx.x & 63;
  const float* x; const float* g; const float* b; unsigned short* y;
  if (row < rowsPer) {
    x = x1 + (size_t)row * DM; g = g1; b = bb1; y = y1 + (size_t)row * DM;
  } else {
    int r2 = row - rowsPer;
    x = x2 + (size_t)r2 * DM; g = g2; b = bb2; y = y2 + (size_t)r2 * DM;
  }
  float a0 = x[lane];
  float a1 = x[lane + 64];
  float a2 = (lane < 32) ? x[lane + 128] : 0.0f;
  float s = a0 + a1 + a2;
#pragma unroll
  for (int m = 1; m < 64; m <<= 1) s += __shfl_xor(s, m);
  float mean = s * (1.0f / DM);
  float d0 = a0 - mean, d1 = a1 - mean, d2 = a2 - mean;
  float vs = d0 * d0 + d1 * d1 + ((lane < 32) ? d2 * d2 : 0.0f);
#pragma unroll
  for (int m = 1; m < 64; m <<= 1) vs += __shfl_xor(vs, m);
  float rstd = rsqrtf(vs * (1.0f / DM) + 1e-5f);
  y[lane]      = f2bf(d0 * rstd * g[lane]      + b[lane]);
  y[lane + 64] = f2bf(d1 * rstd * g[lane + 64] + b[lane + 64]);
  if (lane < 32)
    y[lane + 128] = f2bf(d2 * rstd * g[lane + 128] + b[lane + 128]);
}

// ============ LDS-W GEMM: 64 rows x NCOL*16 cols per block, K=160 ============
// EPI 0 (NCOL=10): qkv (y=0 Q padded / y=1 K chunked / y=2 V slot-chunked)
// EPI 2 (NCOL=10): bias+gelu -> bf16 [row][640] at col offset y*160
// EPI 3 (NCOL=10): bias+res -> f32 [row][160] AND fused LayerNorm -> bf16 Kc
template <int EPI, int NCOL>
__global__ __launch_bounds__(256, 2)
void gemm160_kernel(const unsigned short* __restrict__ Aq,
                    const unsigned short* __restrict__ Akv,
                    const unsigned short* __restrict__ W,
                    const float* __restrict__ bias,
                    const float* __restrict__ res,
                    void* __restrict__ outp,
                    unsigned short* __restrict__ Kc,
                    unsigned short* __restrict__ Vc,
                    const float* __restrict__ lng,
                    const float* __restrict__ lnb) {
  __shared__ unsigned short wl[NCOL * 16 * 168];
  int tid = threadIdx.x;
  int lane = tid & 63;
  int w = tid >> 6;
  int y = blockIdx.y;
  const unsigned short* Wb = W + y * (NCOL * 2560);
  for (int idx = tid * 8; idx < NCOL * 2560; idx += 2048) {
    int col = idx / 160, k = idx % 160;
    *(uint4*)(wl + col * 168 + k) = *(const uint4*)(Wb + idx);
  }
  __syncthreads();
  int lr = lane & 15;
  int g = lane >> 4;
  int R0 = blockIdx.x * 64;
  int rbase = R0 + w * 16;
  const unsigned short* A = (EPI == 0 && y > 0) ? Akv : Aq;
  const unsigned short* Ap = A + (size_t)(rbase + lr) * 160 + g * 8;
  const unsigned short* wp = wl + lr * 168 + g * 8;
  f32x4 acc[NCOL];
#pragma unroll
  for (int c = 0; c < NCOL; ++c) acc[c] = (f32x4){0, 0, 0, 0};
#pragma unroll
  for (int k0 = 0; k0 < 160; k0 += 32) {
    bf16x8 a = *(const bf16x8*)(Ap + k0);
#pragma unroll
    for (int c = 0; c < NCOL; ++c) {
      bf16x8 bfr = *(const bf16x8*)(wp + c * 16 * 168 + k0);
      acc[c] = __builtin_amdgcn_mfma_f32_16x16x32_bf16(a, bfr, acc[c], 0, 0, 0);
    }
  }
  if (EPI == 0) {
    if (y == 0) {
      unsigned short* Qp = (unsigned short*)outp;
#pragma unroll
      for (int c = 0; c < NCOL; ++c) {
        int col = c * 16 + lr;
        int h = col / 20, d = col % 20;
        float bc = bias[col];
#pragma unroll
        for (int r = 0; r < 4; ++r) {
          int row = rbase + g * 4 + r;
          Qp[(size_t)row * 256 + h * 32 + d] = f2bf(acc[c][r] + bc);
        }
      }
    } else if (y == 1) {
      int b = R0 >> 10;
#pragma unroll
      for (int c = 0; c < NCOL; ++c) {
        int col = c * 16 + lr;
        int h = col / 20, d = col % 20;
        float bc = bias[160 + col];
        size_t base = ((((size_t)(b * 8 + h)) * 4 + (d >> 3)) * 1024) * 8 + (d & 7);
#pragma unroll
        for (int r = 0; r < 4; ++r) {
          int tok = (rbase + g * 4 + r) & 1023;
          Kc[base + (size_t)tok * 8] = f2bf(acc[c][r] + bc);
        }
      }
    } else {
      int b = R0 >> 10;
      int base64 = R0 & 1023;
      int slotbase = base64 + g * 8 + (w & 1) * 4 + (w >> 1) * 32;
#pragma unroll
      for (int c = 0; c < NCOL; ++c) {
        int col = c * 16 + lr;
        int h = col / 20, d = col % 20;
        float bc = bias[320 + col];
        size_t vb = ((size_t)(b * 8 + h) * 128) * 256 + (size_t)d * 8;
#pragma unroll
        for (int r = 0; r < 4; ++r) {
          int S = slotbase + r;
          Vc[vb + (size_t)(S >> 3) * 256 + (S & 7)] = f2bf(acc[c][r] + bc);
        }
      }
    }
  } else if (EPI == 2) {
    unsigned short* out = (unsigned short*)outp;
#pragma unroll
    for (int c = 0; c < NCOL; ++c) {
      int colg = y * NCOL * 16 + c * 16 + lr;
      float bc = bias[colg];
#pragma unroll
      for (int r = 0; r < 4; ++r) {
        int row = rbase + g * 4 + r;
        float v = acc[c][r] + bc;
        v = 0.5f * v * (1.0f + erff(v * 0.70710678118654752f));
        out[(size_t)row * 640 + colg] = f2bf(v);
      }
    }
  } else {
    float* out = (float*)outp;
#pragma unroll
    for (int c = 0; c < NCOL; ++c) {
      int col = c * 16 + lr;
      float bc = bias[col];
#pragma unroll
      for (int r = 0; r < 4; ++r) {
        int row = rbase + g * 4 + r;
        float v = acc[c][r] + bc + res[(size_t)row * 160 + col];
        acc[c][r] = v;
        out[(size_t)row * 160 + col] = v;
      }
    }
#pragma unroll
    for (int r = 0; r < 4; ++r) {
      float s = 0.0f, sq = 0.0f;
#pragma unroll
      for (int c = 0; c < NCOL; ++c) { s += acc[c][r]; sq += acc[c][r] * acc[c][r]; }
#pragma unroll
      for (int m = 1; m < 16; m <<= 1) { s += __shfl_xor(s, m); sq += __shfl_xor(sq, m); }
      float mean = s * (1.0f / DM);
      float var = sq * (1.0f / DM) - mean * mean;
      float rstd = rsqrtf(var + 1e-5f);
      int row = rbase + g * 4 + r;
#pragma unroll
      for (int c = 0; c < NCOL; ++c) {
        int col = c * 16 + lr;
        Kc[(size_t)row * 160 + col] =
            f2bf((acc[c][r] - mean) * rstd * lng[col] + lnb[col]);
      }
    }
  }
}

// ---------------- old-style GEMM for w2 (K=640) ----------------
template <int K>
__global__ __launch_bounds__(256, 4)
void gemm_kernel(const unsigned short* __restrict__ A,
                 const unsigned short* __restrict__ W,
                 const float* __restrict__ bias,
                 const float* __restrict__ res,
                 float* __restrict__ out, int N) {
  int lane = threadIdx.x & 63;
  int wid = threadIdx.x >> 6;
  int wr = wid >> 1, wc = wid & 1;
  int r0 = blockIdx.x * 64 + wr * 32;
  int c0 = blockIdx.y * 64 + wc * 32;
  if (c0 >= N) return;
  int lr = lane & 15;
  int ko = (lane >> 4) * 8;
  const unsigned short* Ap0 = A + (size_t)(r0 + lr) * K + ko;
  const unsigned short* Ap1 = Ap0 + (size_t)16 * K;
  const unsigned short* Wp0 = W + (size_t)(c0 + lr) * K + ko;
  const unsigned short* Wp1 = Wp0 + (size_t)16 * K;
  f32x4 acc00 = {0, 0, 0, 0}, acc01 = {0, 0, 0, 0};
  f32x4 acc10 = {0, 0, 0, 0}, acc11 = {0, 0, 0, 0};
#pragma unroll
  for (int k = 0; k < K; k += 32) {
    bf16x8 a0 = *(const bf16x8*)(Ap0 + k);
    bf16x8 a1 = *(const bf16x8*)(Ap1 + k);
    bf16x8 b0 = *(const bf16x8*)(Wp0 + k);
    bf16x8 b1 = *(const bf16x8*)(Wp1 + k);
    acc00 = __builtin_amdgcn_mfma_f32_16x16x32_bf16(a0, b0, acc00, 0, 0, 0);
    acc01 = __builtin_amdgcn_mfma_f32_16x16x32_bf16(a0, b1, acc01, 0, 0, 0);
    acc10 = __builtin_amdgcn_mfma_f32_16x16x32_bf16(a1, b0, acc10, 0, 0, 0);
    acc11 = __builtin_amdgcn_mfma_f32_16x16x32_bf16(a1, b1, acc11, 0, 0, 0);
  }
  int cA = c0 + lr, cB = c0 + 16 + lr;
  float bc0 = bias[cA];
  float bc1 = bias[cB];
  int rb = (lane >> 4) * 4;
#pragma unroll
  for (int i = 0; i < 2; ++i) {
    f32x4 aA = i ? acc10 : acc00;
    f32x4 aB = i ? acc11 : acc01;
#pragma unroll
    for (int r = 0; r < 4; ++r) {
      int row = r0 + i * 16 + rb + r;
      out[(size_t)row * N + cA] = aA[r] + bc0 + res[(size_t)row * N + cA];
      out[(size_t)row * N + cB] = aB[r] + bc1 + res[(size_t)row * N + cB];
    }
  }
}

// ------- flash attention: swapped QK^T, in-register P, KVBLK=128 ------
// (round-14 verified best: shared double-buffer + __syncthreads + setprio)
__global__ __launch_bounds__(256, 4)
void attn_kernel(const unsigned short* __restrict__ Qp,
                 const unsigned short* __restrict__ Kc,
                 const unsigned short* __restrict__ Vc,
                 unsigned short* __restrict__ O,
                 const float* __restrict__ tau_ptr,
                 float base_scale) {
  __shared__ unsigned short kbuf[2][4096];
  __shared__ unsigned short vbuf[2][4096];
  int lane = threadIdx.x & 63;
  int wid = threadIdx.x >> 6;
  int bh = blockIdx.x;
  int b = bh >> 3, h = bh & 7;
  int q0 = blockIdx.y * 128 + wid * 32;
  float sc = base_scale;
  if (tau_ptr) {
    float lt = tau_ptr[0];
    float sp = (lt > 20.0f) ? lt : log1pf(expf(lt));
    sc /= fminf(sp + 0.5f, 2.0f);
  }
  float scale = sc * 1.4426950408889634f;
  int lr = lane & 15;
  int g = lane >> 4;
  int ko = g * 8;
  int rb = g * 4;
  const size_t tb = (size_t)b * LQN;
  union { bf16x8 v; unsigned short s[8]; unsigned int u[4]; } fq0, fq1;
  fq0.v = *(const bf16x8*)(Qp + (tb + q0 + lr) * 256 + h * 32 + ko);
  fq1.v = *(const bf16x8*)(Qp + (tb + q0 + 16 + lr) * 256 + h * 32 + ko);
#pragma unroll
  for (int j = 0; j < 4; ++j) {
    fq0.u[j] = cvtpk(bf2f(fq0.s[2 * j]) * scale, bf2f(fq0.s[2 * j + 1]) * scale);
    fq1.u[j] = cvtpk(bf2f(fq1.s[2 * j]) * scale, bf2f(fq1.s[2 * j + 1]) * scale);
  }
  bf16x8 aq0 = fq0.v, aq1 = fq1.v;
  const unsigned short* ksrc = Kc + (((size_t)bh * 4 + wid) * 1024) * 8;
  const unsigned short* vsrc = Vc + (size_t)bh * 32768;
  int sd = wid * 1024 + lane * 8;
  {
    uint4 k0 = *(const uint4*)(ksrc + lane * 8);
    uint4 k1 = *(const uint4*)(ksrc + (64 + lane) * 8);
    uint4 v0 = *(const uint4*)(vsrc + sd);
    uint4 v1 = *(const uint4*)(vsrc + sd + 512);
    *(uint4*)(kbuf[0] + sd) = k0;
    *(uint4*)(kbuf[0] + sd + 512) = k1;
    *(uint4*)(vbuf[0] + sd) = v0;
    *(uint4*)(vbuf[0] + sd + 512) = v1;
  }
  __syncthreads();
  int cur = 0;
  f32x4 o00 = {0, 0, 0, 0}, o01 = {0, 0, 0, 0};
  f32x4 o10 = {0, 0, 0, 0}, o11 = {0, 0, 0, 0};
  const f32x4 zero = {0, 0, 0, 0};

#define ATTN_COMPUTE(KB, VB)                                                   \
  {                                                                            \
    const unsigned short* kp_ = (KB);                                          \
    const unsigned short* vp_ = (VB);                                          \
    bf16x8 ck0 = *(const bf16x8*)(kp_ + g * 1024 + lr * 8);                    \
    bf16x8 ck1 = *(const bf16x8*)(kp_ + g * 1024 + (16 + lr) * 8);             \
    bf16x8 ck2 = *(const bf16x8*)(kp_ + g * 1024 + (32 + lr) * 8);             \
    bf16x8 ck3 = *(const bf16x8*)(kp_ + g * 1024 + (48 + lr) * 8);             \
    __builtin_amdgcn_s_setprio(1);                                             \
    f32x4 s0 = __builtin_amdgcn_mfma_f32_16x16x32_bf16(ck0, aq0, zero, 0, 0, 0);\
    f32x4 s1 = __builtin_amdgcn_mfma_f32_16x16x32_bf16(ck1, aq0, zero, 0, 0, 0);\
    f32x4 s2 = __builtin_amdgcn_mfma_f32_16x16x32_bf16(ck2, aq0, zero, 0, 0, 0);\
    f32x4 s3 = __builtin_amdgcn_mfma_f32_16x16x32_bf16(ck3, aq0, zero, 0, 0, 0);\
    __builtin_amdgcn_s_setprio(0);                                             \
    union { bf16x8 v; unsigned int u[4]; } p1, p2, p3, p4;                     \
    p1.u[0] = cvtpk(ex2(s0[0]), ex2(s0[1]));                                   \
    p1.u[1] = cvtpk(ex2(s0[2]), ex2(s0[3]));                                   \
    p1.u[2] = cvtpk(ex2(s1[0]), ex2(s1[1]));                                   \
    p1.u[3] = cvtpk(ex2(s1[2]), ex2(s1[3]));                                   \
    p2.u[0] = cvtpk(ex2(s2[0]), ex2(s2[1]));                                   \
    p2.u[1] = cvtpk(ex2(s2[2]), ex2(s2[3]));                                   \
    p2.u[2] = cvtpk(ex2(s3[0]), ex2(s3[1]));                                   \
    p2.u[3] = cvtpk(ex2(s3[2]), ex2(s3[3]));                                   \
    __builtin_amdgcn_s_setprio(1);                                             \
    s0 = __builtin_amdgcn_mfma_f32_16x16x32_bf16(ck0, aq1, zero, 0, 0, 0);     \
    s1 = __builtin_amdgcn_mfma_f32_16x16x32_bf16(ck1, aq1, zero, 0, 0, 0);     \
    s2 = __builtin_amdgcn_mfma_f32_16x16x32_bf16(ck2, aq1, zero, 0, 0, 0);     \
    s3 = __builtin_amdgcn_mfma_f32_16x16x32_bf16(ck3, aq1, zero, 0, 0, 0);     \
    __builtin_amdgcn_s_setprio(0);                                             \
    p3.u[0] = cvtpk(ex2(s0[0]), ex2(s0[1]));                                   \
    p3.u[1] = cvtpk(ex2(s0[2]), ex2(s0[3]));                                   \
    p3.u[2] = cvtpk(ex2(s1[0]), ex2(s1[1]));                                   \
    p3.u[3] = cvtpk(ex2(s1[2]), ex2(s1[3]));                                   \
    p4.u[0] = cvtpk(ex2(s2[0]), ex2(s2[1]));                                   \
    p4.u[1] = cvtpk(ex2(s2[2]), ex2(s2[3]));                                   \
    p4.u[2] = cvtpk(ex2(s3[0]), ex2(s3[1]));                                   \
    p4.u[3] = cvtpk(ex2(s3[2]), ex2(s3[3]));                                   \
    bf16x8 w00 = *(const bf16x8*)(vp_ + g * 256 + lr * 8);                     \
    bf16x8 w01 = *(const bf16x8*)(vp_ + (4 + g) * 256 + lr * 8);               \
    bf16x8 w10 = *(const bf16x8*)(vp_ + g * 256 + (16 + lr) * 8);              \
    bf16x8 w11 = *(const bf16x8*)(vp_ + (4 + g) * 256 + (16 + lr) * 8);        \
    __builtin_amdgcn_s_setprio(1);                                             \
    o00 = __builtin_amdgcn_mfma_f32_16x16x32_bf16(p1.v, w00, o00, 0, 0, 0);    \
    o00 = __builtin_amdgcn_mfma_f32_16x16x32_bf16(p2.v, w01, o00, 0, 0, 0);    \
    o01 = __builtin_amdgcn_mfma_f32_16x16x32_bf16(p1.v, w10, o01, 0, 0, 0);    \
    o01 = __builtin_amdgcn_mfma_f32_16x16x32_bf16(p2.v, w11, o01, 0, 0, 0);    \
    o10 = __builtin_amdgcn_mfma_f32_16x16x32_bf16(p3.v, w00, o10, 0, 0, 0);    \
    o10 = __builtin_amdgcn_mfma_f32_16x16x32_bf16(p4.v, w01, o10, 0, 0, 0);    \
    o11 = __builtin_amdgcn_mfma_f32_16x16x32_bf16(p3.v, w10, o11, 0, 0, 0);    \
    o11 = __builtin_amdgcn_mfma_f32_16x16x32_bf16(p4.v, w11, o11, 0, 0, 0);    \
    __builtin_amdgcn_s_setprio(0);                                             \
  }

#pragma unroll 1
  for (int kt = 0; kt < LKN; kt += 128) {
    int ktn = (kt + 128 < LKN) ? kt + 128 : 0;
    uint4 kA0 = *(const uint4*)(ksrc + (ktn + lane) * 8);
    uint4 kA1 = *(const uint4*)(ksrc + (ktn + 64 + lane) * 8);
    uint4 vA0 = *(const uint4*)(vsrc + ktn * 32 + sd);
    uint4 vA1 = *(const uint4*)(vsrc + ktn * 32 + sd + 512);
    ATTN_COMPUTE(kbuf[cur], vbuf[cur])
    *(uint4*)(kbuf[cur ^ 1] + sd) = kA0;
    *(uint4*)(kbuf[cur ^ 1] + sd + 512) = kA1;
    ATTN_COMPUTE(kbuf[cur] + 512, vbuf[cur] + 2048)
    *(uint4*)(vbuf[cur ^ 1] + sd) = vA0;
    *(uint4*)(vbuf[cur ^ 1] + sd + 512) = vA1;
    __syncthreads();
    cur ^= 1;
  }
#undef ATTN_COMPUTE
  unsigned short* ob = O + (tb + q0) * DM + h * HDIM;
  int psl = (lane & 48) + 4;
#pragma unroll
  for (int r = 0; r < 4; ++r) {
    int qr = rb + r;
    float inv0 = 1.0f / __shfl(o01[r], psl, 64);
    ob[(size_t)qr * DM + lr] = f2bf(o00[r] * inv0);
    if (lr < 4) ob[(size_t)qr * DM + 16 + lr] = f2bf(o01[r] * inv0);
    float inv1 = 1.0f / __shfl(o11[r], psl, 64);
    ob[(size_t)(16 + qr) * DM + lr] = f2bf(o10[r] * inv1);
    if (lr < 4) ob[(size_t)(16 + qr) * DM + 16 + lr] = f2bf(o11[r] * inv1);
  }
}

extern "C" void kernel_launch(void* const* d_in, const int* in_sizes, int n_in,
                              void* d_out, int out_size, void* d_ws, size_t ws_size,
                              hipStream_t stream) {
  (void)in_sizes; (void)n_in; (void)out_size; (void)ws_size;
  const float* q        = (const float*)d_in[0];
  const float* kv       = (const float*)d_in[1];
  const float* ln1_g    = (const float*)d_in[2];
  const float* ln1_b    = (const float*)d_in[3];
  const float* sa_in_w  = (const float*)d_in[4];
  const float* sa_in_b  = (const float*)d_in[5];
  const float* sa_out_w = (const float*)d_in[6];
  const float* sa_out_b = (const float*)d_in[7];
  const float* ln2_g    = (const float*)d_in[8];
  const float* ln2_b    = (const float*)d_in[9];
  const float* lnkv_g   = (const float*)d_in[10];
  const float* lnkv_b   = (const float*)d_in[11];
  const float* ca_qw    = (const float*)d_in[12];
  const float* ca_qb    = (const float*)d_in[13];
  const float* ca_kw    = (const float*)d_in[14];
  const float* ca_kb    = (const float*)d_in[15];
  const float* ca_vw    = (const float*)d_in[16];
  const float* ca_vb    = (const float*)d_in[17];
  const float* ca_ow    = (const float*)d_in[18];
  const float* ca_ob    = (const float*)d_in[19];
  const float* log_tau  = (const float*)d_in[20];
  const float* lnf_g    = (const float*)d_in[21];
  const float* lnf_b    = (const float*)d_in[22];
  const float* w1       = (const float*)d_in[23];
  const float* b1       = (const float*)d_in[24];
  const float* w2       = (const float*)d_in[25];
  const float* b2       = (const float*)d_in[26];

  const int M = NB * LQN;  // 16384 rows
  char* ws = (char*)d_ws;
  unsigned short* wb   = (unsigned short*)(ws);
  float*          bcat = (float*)(ws + 860160);
  unsigned short* qn   = (unsigned short*)(ws + 1048576);
  unsigned short* sqp  = (unsigned short*)(ws + 6291456);
  unsigned short* skc  = (unsigned short*)(ws + 14680064);
  unsigned short* svc  = (unsigned short*)(ws + 23068672);
  unsigned short* attn = (unsigned short*)(ws + 31457280);
  unsigned short* kvn  = (unsigned short*)(ws + 36700160);
  float*          q1   = (float*)(ws + 41943040);
  float*          q2   = (float*)(ws + 52428800);
  unsigned short* hbuf = (unsigned short*)(ws + 6291456);  // FFN phase reuse

  unsigned short* b_sa_in  = wb;            // 76800 (Q|K|V contiguous)
  unsigned short* b_sa_out = wb + 76800;    // 25600
  unsigned short* b_ca_q   = wb + 102400;   // 25600 (q|k|v contiguous)
  unsigned short* b_ca_o   = wb + 179200;   // 25600
  unsigned short* b_w1     = wb + 204800;   // 102400
  unsigned short* b_w2     = wb + 307200;   // 102400

  dim3 blk(256);
  const float isq = 0.22360679774997896f;  // 1/sqrt(20)

  CvtArgs ca;
  ca.src[0] = sa_in_w;  ca.src[1] = sa_out_w; ca.src[2] = ca_qw; ca.src[3] = ca_kw;
  ca.src[4] = ca_vw;    ca.src[5] = ca_ow;    ca.src[6] = w1;    ca.src[7] = w2;
  int cum[9] = {0, 76800, 102400, 128000, 153600, 179200, 204800, 307200, 409600};
  for (int i = 0; i < 9; ++i) ca.cum[i] = cum[i];
  init_kernel<<<dim3(M / 2), blk, 0, stream>>>(
      (uint4*)(ws + 6291456), 1048576, (uint4*)(ws + 23068672), 524288,
      ca_qb, ca_kb, ca_vb, bcat, ca, wb,
      q, ln1_g, ln1_b, qn, kv, lnkv_g, lnkv_b, kvn, M);

  // --- self attention block ---
  gemm160_kernel<0, 10><<<dim3(M / 64, 3), blk, 0, stream>>>(
      qn, qn, b_sa_in, sa_in_b, nullptr, sqp, skc, svc, nullptr, nullptr);
  attn_kernel<<<dim3(NB * NHEADS, LQN / 128), blk, 0, stream>>>(sqp, skc, svc, attn, nullptr, isq);
  gemm160_kernel<3, 10><<<dim3(M / 64, 1), blk, 0, stream>>>(
      attn, attn, b_sa_out, sa_out_b, q, q1, qn, nullptr, ln2_g, ln2_b);

  // --- cross attention block ---
  gemm160_kernel<0, 10><<<dim3(M / 64, 3), blk, 0, stream>>>(
      qn, kvn, b_ca_q, bcat, nullptr, sqp, skc, svc, nullptr, nullptr);
  attn_kernel<<<dim3(NB * NHEADS, LQN / 128), blk, 0, stream>>>(sqp, skc, svc, attn, log_tau, isq);
  gemm160_kernel<3, 10><<<dim3(M / 64, 1), blk, 0, stream>>>(
      attn, attn, b_ca_o, ca_ob, q1, q2, qn, nullptr, lnf_g, lnf_b);

  // --- FFN ---
  gemm160_kernel<2, 10><<<dim3(M / 64, 4), blk, 0, stream>>>(
      qn, qn, b_w1, b1, nullptr, hbuf, nullptr, nullptr, nullptr, nullptr);
  gemm_kernel<640><<<dim3(M / 64, 3), blk, 0, stream>>>(hbuf, b_w2, b2, q2, (float*)d_out, 160);
}